// Round 14
// baseline (1301.595 us; speedup 1.0000x reference)
//
#include <hip/hip_runtime.h>

typedef unsigned long long ULL;
typedef double v4d __attribute__((ext_vector_type(4)));

// B=8, Cin=Cout=256, H=W=64, A=9, N=36864/batch, PRE=1000, POST=300

__device__ __forceinline__ ULL fkey64(double f) {
    ULL u = (ULL)__double_as_longlong(f);
    return (u & 0x8000000000000000ull) ? ~u : (u | 0x8000000000000000ull);
}

// ---------------- kernel 1: prep (merged): MFMA weight layout + clf diff weights ------------
// wmf layout: [cc 0..63][cg 0..3][tap 0..8][cil 0..3][co 0..63] fp64 (4.72 MB). Each (cc,cg)
// slab is 2304 doubles = 18432 B contiguous -> conv stages it linearly (9 doubles/thread).
__global__ void prep_all(const float* __restrict__ wconv,
                         const float* __restrict__ wclf, const float* __restrict__ bclf,
                         double* __restrict__ wmf,
                         double* __restrict__ wdiff, double* __restrict__ bdiff) {
    int blk = blockIdx.x;
    if (blk < 2304) {
        int e = blk * 256 + threadIdx.x;   // 589824 total
        int co = e & 63;
        int r = e >> 6;                    // 0..9215 = ((cc*4+cg)*9+tap)*4+cil
        int cil = r & 3;
        int r2 = r >> 2;                   // (cc*4+cg)*9+tap
        int tap = r2 % 9;
        int r3 = r2 / 9;                   // cc*4+cg
        int cg = r3 & 3;
        int cc = r3 >> 2;
        int ci = cc * 4 + cil;
        int gco = cg * 64 + co;
        wmf[e] = (double)wconv[(gco * 256 + ci) * 9 + tap];
    } else {
        int a = blk - 2304;                // 0..8
        int c = threadIdx.x;
        wdiff[a * 256 + c] = (double)wclf[(9 + a) * 256 + c] - (double)wclf[a * 256 + c];
        if (c == 0) bdiff[a] = (double)bclf[9 + a] - (double)bclf[a];
    }
}

// ---------------- kernel 2: 3x3 conv + bias + relu via v_mfma_f64_16x16x4, M=128 ------------
// EXACT r12 kernel (629 us, MfmaUtil 84%) -- r13's barrier-free streaming REGRESSED (709 us,
// MfmaUtil 74): B-frags direct from L2 put ~200cyc loads on the MFMA critical path and the
// 64-VGPR budget couldn't hoist 36 frags/chunk -> per-tap vmcnt stalls. LDS staging is load-
// bearing here (converts 36 L2 reads into ds_reads off the critical path). Reverted; settled.
// Conv ladder: 857(VALU)->682->650->629(M=128); streaming=708 refuted; occupancy swept.
// Implicit GEMM: M=128 (two rows/block), N=64 (cg quarter), K=2304 (64 chunks x 9 taps x 4ci).
// Per chunk the SAME 18KB w slab feeds 72 MFMAs/wave; each B-frag ds_read feeds 2 MFMAs.
// Wave w owns cols [w*16,w*16+16) of BOTH rows x all 4 N-tiles (acc 2x4 v4d = 64 VGPR).
// A/B layouts cardinality-forced: A[m=lane&15][k=lane>>4], B[k=lane>>4][n=lane&15];
// D layout via runtime probe (2 throwaway MFMAs) -- correct for ANY f64 D lane-mapping.
__global__ __launch_bounds__(256)
__attribute__((amdgpu_waves_per_eu(4, 4)))
void conv3x3_mfma_f64(
    const float* __restrict__ xin, const double* __restrict__ wmf,
    const float* __restrict__ bias, double* __restrict__ y)
{
    __shared__ double wlds[2304];   // [tap][cil][co64]  18432 B
    __shared__ float  xs[1152];     // [cil 0..3][row 0..3 = h0-1..h0+2][72]; col c = input col c-1

    const int t = threadIdx.x;
    const int blk = blockIdx.x;
    const int b = blk >> 7;            // 8 batches x 128 blocks
    const int rp = (blk >> 2) & 31;    // row pair
    const int cg = blk & 3;
    const int h0 = rp * 2;
    const int lane = t & 63;
    const int wid = t >> 6;            // wave id = column tile
    const int arow = lane & 15;        // A-row (pixel in tile) == B-col (co in tile)
    const int kq = lane >> 4;          // k index (cil) for A and B frags

    // x staging decomposition: 4 cil * 4 rows (h0-1..h0+2) * 66 cols = 1056 elems
    int x_ld[5], x_go[5];
#pragma unroll
    for (int i = 0; i < 5; i++) {
        int e = t + i * 256;
        x_ld[i] = -1; x_go[i] = -1;
        if (e < 1056) {
            int cil = e / 264; int rem = e - cil * 264;
            int row = rem / 66; int c = rem - row * 66;
            int hh = h0 - 1 + row; int col = c - 1;
            x_ld[i] = cil * 288 + row * 72 + c;
            if (hh >= 0 && hh < 64 && col >= 0 && col < 64)
                x_go[i] = cil * 4096 + hh * 64 + col;
        }
    }

    const float* xb = xin + (size_t)b * 1048576;
    const double* wsrc = wmf + (size_t)cg * 2304;   // + cc*9216 per chunk

    // ---- D-layout probe: exact (row,col) of acc element g for this lane ----
    v4d pz = {0.0, 0.0, 0.0, 0.0};
    v4d prow = __builtin_amdgcn_mfma_f64_16x16x4f64((double)arow, 1.0, pz, 0, 0, 0);
    v4d pcol = __builtin_amdgcn_mfma_f64_16x16x4f64(1.0, (double)arow, pz, 0, 0, 0);
    int rmap[4], cmap[4];
#pragma unroll
    for (int g = 0; g < 4; g++) {
        rmap[g] = (int)(prow[g] * 0.25 + 0.5);
        cmap[g] = (int)(pcol[g] * 0.25 + 0.5);
    }

    // preload chunk 0 into regs
    float xreg[5];
    double wreg[9];
#pragma unroll
    for (int i = 0; i < 5; i++)
        xreg[i] = (x_ld[i] >= 0 && x_go[i] >= 0) ? xb[x_go[i]] : 0.f;
#pragma unroll
    for (int i = 0; i < 9; i++) wreg[i] = wsrc[t + i * 256];

    v4d acc0[4], acc1[4];              // row h0 / row h0+1
#pragma unroll
    for (int nt = 0; nt < 4; nt++) {
        acc0[nt] = (v4d){0.0, 0.0, 0.0, 0.0};
        acc1[nt] = (v4d){0.0, 0.0, 0.0, 0.0};
    }

    for (int cc = 0; cc < 64; ++cc) {
        __syncthreads();   // previous compute done before LDS overwrite
#pragma unroll
        for (int i = 0; i < 5; i++) if (x_ld[i] >= 0) xs[x_ld[i]] = xreg[i];
#pragma unroll
        for (int i = 0; i < 9; i++) wlds[t + i * 256] = wreg[i];
        __syncthreads();

        // prefetch next chunk into regs (overlaps with compute below)
        if (cc < 63) {
#pragma unroll
            for (int i = 0; i < 5; i++)
                xreg[i] = (x_ld[i] >= 0 && x_go[i] >= 0) ? xb[(cc + 1) * 16384 + x_go[i]] : 0.f;
#pragma unroll
            for (int i = 0; i < 9; i++) wreg[i] = wsrc[(size_t)(cc + 1) * 9216 + t + i * 256];
        }

        // compute chunk cc: 9 taps x (2 A scalars, 4 shared B frags, 8 MFMA)
        const float* xsp = xs + kq * 288 + wid * 16 + arow;
        const double* wsp = wlds + kq * 64 + arow;
#pragma unroll
        for (int kh = 0; kh < 3; kh++) {
#pragma unroll
            for (int kw = 0; kw < 3; kw++) {
                const int tap = kh * 3 + kw;
                double a0 = (double)xsp[kh * 72 + kw];
                double a1 = (double)xsp[(kh + 1) * 72 + kw];
#pragma unroll
                for (int nt = 0; nt < 4; nt++) {
                    double bf = wsp[tap * 256 + nt * 16];
                    acc0[nt] = __builtin_amdgcn_mfma_f64_16x16x4f64(a0, bf, acc0[nt], 0, 0, 0);
                    acc1[nt] = __builtin_amdgcn_mfma_f64_16x16x4f64(a1, bf, acc1[nt], 0, 0, 0);
                }
            }
        }
    }

    // epilogue: bias + relu (fp64), store NHWC fp64 via probed D maps (layout-agnostic)
    const size_t pix0 = (size_t)(b * 4096 + h0 * 64 + wid * 16);
#pragma unroll
    for (int nt = 0; nt < 4; nt++) {
#pragma unroll
        for (int g = 0; g < 4; g++) {
            int co = cg * 64 + nt * 16 + cmap[g];
            double bv = (double)bias[co];
            y[(pix0 + rmap[g]) * 256 + co]      = fmax(acc0[nt][g] + bv, 0.0);
            y[(pix0 + 64 + rmap[g]) * 256 + co] = fmax(acc1[nt][g] + bv, 0.0);
        }
    }
}

// ---------------- kernel 3: clf head, wave-per-pixel (coalesced y + butterfly reduce) -------
__global__ __launch_bounds__(256) void head_clf2w(
    const double* __restrict__ y, const double* __restrict__ wdiff,
    const double* __restrict__ bdiff, double* __restrict__ dlog)
{
    const int px = blockIdx.x * 4 + (threadIdx.x >> 6);   // 0..32767 (= b*4096 + pix)
    const int lane = threadIdx.x & 63;

    const double* yr = y + (size_t)px * 256;
    double yv[4];
#pragma unroll
    for (int k = 0; k < 4; k++) yv[k] = yr[lane + k * 64];

    double s[9];
#pragma unroll
    for (int a = 0; a < 9; a++) {
        const double* wr = wdiff + a * 256;
        double v = 0.0;
#pragma unroll
        for (int k = 0; k < 4; k++) v = fma(wr[lane + k * 64], yv[k], v);
        s[a] = v;
    }
#pragma unroll
    for (int off = 32; off > 0; off >>= 1) {
#pragma unroll
        for (int a = 0; a < 9; a++) s[a] += __shfl_xor(s[a], off);
    }
    if (lane < 9) dlog[(size_t)px * 9 + lane] = s[lane] + bdiff[lane];
}

// ---------------- kernel 4: exact top-1000, radix-select with PARALLEL bucket-find ----------
// r9-verified (-40 us vs serial scan). Wave 0: lane l folds 8 replicas for buckets 4l..4l+3,
// 6-step __shfl_down inclusive suffix sum, __ballot boundary find, 4-way bucket resolve.
// Selection semantics bit-identical to the original serial loop.
__global__ __launch_bounds__(1024, 1) void topk1000(
    const double* __restrict__ dlog, int* __restrict__ selidx)
{
    const int b = blockIdx.x;
    const int t = threadIdx.x;
    const double* d = dlog + (size_t)b * 36864;

    ULL key[36];                      // 36864 = 36 * 1024, coalesced; 72 VGPRs
#pragma unroll
    for (int j = 0; j < 36; j++) key[j] = fkey64(d[t + j * 1024]);

    __shared__ unsigned int hist[2048];   // 8 replicas x 256 buckets
    __shared__ ULL sh_prefix;
    __shared__ unsigned int sh_need;
    const int rep = (t >> 6) & 7;         // wave id mod 8 -> replica

    ULL prefix = 0ull;
    int need = 1000;
    for (int rs = 56; rs >= 0; rs -= 8) {
        hist[t] = 0u; hist[t + 1024] = 0u;
        __syncthreads();
        ULL mhi = (rs == 56) ? 0ull : (~0ull << (rs + 8));
#pragma unroll
        for (int j = 0; j < 36; j++) {
            ULL u = key[j];
            if ((u & mhi) == prefix)
                atomicAdd(&hist[rep * 256 + ((unsigned int)(u >> rs) & 255u)], 1u);
        }
        __syncthreads();
        if (t < 64) {                     // wave 0: fold + parallel bucket-find
            unsigned int c[4];
#pragma unroll
            for (int j = 0; j < 4; j++) {
                unsigned int s = 0u;
#pragma unroll
                for (int rr = 0; rr < 8; rr++) s += hist[rr * 256 + 4 * t + j];
                c[j] = s;
            }
            const unsigned int s4 = c[0] + c[1] + c[2] + c[3];
            unsigned int S = s4;          // inclusive suffix sum across lanes
#pragma unroll
            for (int off = 1; off < 64; off <<= 1) {
                unsigned int o = __shfl_down(S, off);
                if (t + off < 64) S += o;
            }
            ULL m = __ballot(S >= (unsigned int)need);   // bit l set iff S_l >= need
            int lstar = 63 - __builtin_clzll(m);         // m != 0: S_0 = total >= need
            if (t == lstar) {
                const unsigned int T = S - s4;           // suffix of lanes > lstar
                const unsigned int nd = (unsigned int)need;
                int vs; unsigned int ca;                 // bucket, count strictly above it
                if (T + c[3] >= nd)                    { vs = 4 * t + 3; ca = T; }
                else if (T + c[3] + c[2] >= nd)        { vs = 4 * t + 2; ca = T + c[3]; }
                else if (T + c[3] + c[2] + c[1] >= nd) { vs = 4 * t + 1; ca = T + c[3] + c[2]; }
                else                    { vs = 4 * t;     ca = T + c[3] + c[2] + c[1]; }
                sh_prefix = prefix | ((ULL)vs << rs);
                sh_need = nd - ca;
            }
        }
        __syncthreads();
        prefix = sh_prefix;
        need = (int)sh_need;
    }

    const ULL K = prefix;                    // exact fp64 key of the 1000th largest
    const int count_above = 1000 - need;     // strictly greater than K
    __shared__ ULL skey[1024];
    __shared__ int sidx[1024];
    __shared__ unsigned int cgt, ceq;
    if (t == 0) { cgt = 0u; ceq = 0u; }
    skey[t] = ~0ull;
    sidx[t] = 0x7FFFFFFF;
    __syncthreads();
#pragma unroll
    for (int j = 0; j < 36; j++) {
        ULL u = key[j];
        int i = t + j * 1024;
        if (u > K) {
            unsigned int s = atomicAdd(&cgt, 1u);
            skey[s] = ~u; sidx[s] = i;
        } else if (u == K) {
            unsigned int s = atomicAdd(&ceq, 1u) + (unsigned int)count_above;
            if (s < 1024u) { skey[s] = ~u; sidx[s] = i; }
        }
    }
    __syncthreads();
    // bitonic sort ascending on (key, idx): == score desc, index asc on ties
    for (int k = 2; k <= 1024; k <<= 1) {
        for (int j = k >> 1; j > 0; j >>= 1) {
            int ixj = t ^ j;
            if (ixj > t) {
                ULL ka = skey[t], kb = skey[ixj];
                int ia = sidx[t], ib = sidx[ixj];
                bool up = ((t & k) == 0);
                bool gt = (ka > kb) || (ka == kb && ia > ib);
                bool lt = (ka < kb) || (ka == kb && ia < ib);
                if (up ? gt : lt) {
                    skey[t] = kb; skey[ixj] = ka;
                    sidx[t] = ib; sidx[ixj] = ia;
                }
            }
            __syncthreads();
        }
    }
    if (t < 1000) selidx[b * 1000 + t] = sidx[t];
}

// ---------------- kernel 5: reg head, wave-per-roi, direct-L2 weights -----------------------
// r10-verified: no LDS staging (anchor is wave-uniform -> 97% of the old 36KB stage was
// waste); wregp read directly through L2, more resident blocks hide scattered y reads.
__global__ __launch_bounds__(256) void decode_boxes2(
    const double* __restrict__ y, const int* __restrict__ selidx,
    const float* __restrict__ wregp, const float* __restrict__ bregp,
    const float* __restrict__ anchors, double4* __restrict__ boxes)
{
    const int roi  = (blockIdx.x * 256 + threadIdx.x) >> 6;   // 0..7999
    const int lane = threadIdx.x & 63;
    const int b = roi / 1000;
    const int n = selidx[roi];                  // wave-uniform
    const int a = n % 9;
    const int pix = n / 9;

    const double2* yrow = (const double2*)(y + ((size_t)(b * 4096 + pix)) * 256);
    double2 ya = yrow[lane];
    double2 yc = yrow[lane + 64];

    double s[4];
#pragma unroll
    for (int c = 0; c < 4; c++) {
        const float* wp = wregp + (4 * a + c) * 256;
        float2 wa = *(const float2*)(wp + 2 * lane);
        float2 wc = *(const float2*)(wp + 128 + 2 * lane);
        double v = 0.0;
        v = fma((double)wa.x, ya.x, v);
        v = fma((double)wa.y, ya.y, v);
        v = fma((double)wc.x, yc.x, v);
        v = fma((double)wc.y, yc.y, v);
        s[c] = v;
    }
#pragma unroll
    for (int off = 32; off > 0; off >>= 1) {
#pragma unroll
        for (int c = 0; c < 4; c++) s[c] += __shfl_xor(s[c], off);
    }

    if (lane == 0) {
        double a0 = s[0] + (double)bregp[4 * a + 0];
        double a1 = s[1] + (double)bregp[4 * a + 1];
        double a2 = s[2] + (double)bregp[4 * a + 2];
        double a3 = s[3] + (double)bregp[4 * a + 3];
        float4 an = ((const float4*)anchors)[n];
        double ax1 = an.x, ay1 = an.y, ax2 = an.z, ay2 = an.w;
        double aw = ax2 - ax1, ah = ay2 - ay1;
        double cx = 0.5 * (ax1 + ax2), cy = 0.5 * (ay1 + ay2);
        double pcx = a0 * aw + cx, pcy = a1 * ah + cy;
        double pw = exp(a2) * aw, ph = exp(a3) * ah;
        double x1b = pcx - 0.5 * pw, y1b = pcy - 0.5 * ph;
        double x2b = pcx + 0.5 * pw, y2b = pcy + 0.5 * ph;
        x1b = fmin(fmax(x1b, 0.0), 1023.0);
        y1b = fmin(fmax(y1b, 0.0), 1023.0);
        x2b = fmin(fmax(x2b, 0.0), 1023.0);
        y2b = fmin(fmax(y2b, 0.0), 1023.0);
        double4 o; o.x = x1b; o.y = y1b; o.z = x2b; o.w = y2b;
        boxes[roi] = o;
    }
}

// ---------------- kernel 6: FUSED NMS: in-LDS mask build + greedy scan + compaction ---------
// r14: nms_mask_k + nms_scan_k fused into one 8-block kernel. The 125KB mask is built
// directly in LDS (no 1MB global write+read, no extra launch, no cross-XCD round-trip).
// LDS: smask 128000 + bx 32000 + keepw 128 = 160,128 B <= 163,840. Mask math and scan
// logic verbatim from the r10-verified kernels (word index m = i*16 + wc preserved).
// pf[] indexed ONLY by compile-time constants (r5 bug: dynamic pf[i&15] -> scratch).
__global__ __launch_bounds__(1024) void nms_fused_k(
    const double4* __restrict__ boxes, float* __restrict__ out)
{
    int b = blockIdx.x;
    int t = threadIdx.x;
    __shared__ double4 bx[1000];   //  32000 B
    __shared__ ULL smask[16000];   // 128000 B
    __shared__ ULL keepw[16];
    for (int i = t; i < 1000; i += 1024) bx[i] = boxes[b * 1000 + i];
    __syncthreads();
    // build suppression bitmask in LDS (verbatim nms_mask_k body, m over full 0..15999)
    for (int m = t; m < 16000; m += 1024) {
        int i = m >> 4;
        int wc = m & 15;
        ULL bits = 0ull;
        int j0 = wc << 6;
        if (j0 + 63 > i) {
            double4 bi = bx[i];
            double ai = (bi.z - bi.x) * (bi.w - bi.y);
            int js = max(j0, i + 1);
            int je = min(j0 + 64, 1000);
            for (int j = js; j < je; j++) {
                double4 bj = bx[j];
                double lx = fmax(bi.x, bj.x), ly = fmax(bi.y, bj.y);
                double ux = fmin(bi.z, bj.z), uy = fmin(bi.w, bj.w);
                double iw = fmax(ux - lx, 0.0), ih = fmax(uy - ly, 0.0);
                double inter = iw * ih;
                double aj = (bj.z - bj.x) * (bj.w - bj.y);
                double iou = inter / (ai + aj - inter);
                if (iou > 0.7) bits |= (1ull << (j - j0));
            }
        }
        smask[m] = bits;
    }
    __syncthreads();
    if (t < 64) {           // wave 0: sequential greedy scan (verbatim r10 logic)
        int lane = t;
        ULL remv = 0ull, cur = 0ull;
        ULL pf[16];
#pragma unroll
        for (int q = 0; q < 16; q++) pf[q] = (lane < 16) ? smask[q * 16 + lane] : 0ull;
        for (int base = 0; base < 1000; base += 16) {
#pragma unroll
            for (int q = 0; q < 16; q++) {
                int i = base + q;
                if (i < 1000) {
                    ULL m = pf[q];
                    int c = i >> 6;
                    ULL mc = __shfl(m, c);
                    bool rem = ((cur >> (i & 63)) & 1ull) != 0ull;
                    if (!rem) { remv |= m; cur |= mc; }
                    if (((i + 1) & 63) == 0) cur = __shfl(remv, (i + 1) >> 6);
                    int nx = i + 16;
                    pf[q] = (lane < 16 && nx < 1000) ? smask[nx * 16 + lane] : 0ull;
                }
            }
        }
        if (lane < 16) keepw[lane] = ~remv;
    }
    __syncthreads();
    if (t < 300) {
        float* row = out + (size_t)(b * 300 + t) * 5;
        row[0] = (float)b; row[1] = 0.f; row[2] = 0.f; row[3] = 0.f; row[4] = 0.f;
    }
    __syncthreads();
    if (t < 1000) {
        ULL kw = keepw[t >> 6];
        if ((kw >> (t & 63)) & 1ull) {
            int pos = (int)__popcll(kw & ((1ull << (t & 63)) - 1ull));
            for (int w = 0; w < (t >> 6); w++) pos += (int)__popcll(keepw[w]);
            if (pos < 300) {
                double4 bv = bx[t];
                float* row = out + (size_t)(b * 300 + pos) * 5;
                row[1] = (float)bv.x; row[2] = (float)bv.y;
                row[3] = (float)bv.z; row[4] = (float)bv.w;
            }
        }
    }
}

// ---------------- launcher ----------------
extern "C" void kernel_launch(void* const* d_in, const int* in_sizes, int n_in,
                              void* d_out, int out_size, void* d_ws, size_t ws_size,
                              hipStream_t stream)
{
    const float* xin     = (const float*)d_in[0];
    const float* anchors = (const float*)d_in[2];
    const float* wconv   = (const float*)d_in[3];
    const float* bconv   = (const float*)d_in[4];
    const float* wclf    = (const float*)d_in[5];
    const float* bclf    = (const float*)d_in[6];
    const float* wregp   = (const float*)d_in[7];
    const float* bregp   = (const float*)d_in[8];
    float* out = (float*)d_out;

    // ws layout (~74.2 MB; wmf's region is reused by boxes/selidx after conv):
    char* base = (char*)d_ws;
    double*  y      = (double*)(base);              // 67,108,864 B  [conv out, fp64 NHWC]
    double*  wmf    = (double*)(base + 67108864);   //  4,718,592 B  [live: prep -> conv]
    double4* boxes  = (double4*)(base + 67108864);  //    256,000 B  [live: decode -> end]
    int*     selidx = (int*)(base + 68388864);      //     32,000 B
    double*  dlog   = (double*)(base + 71827456);   //  2,359,296 B
    double*  wdiff  = (double*)(base + 74186752);   //     18,432 B
    double*  bdiff  = (double*)(base + 74205184);   //         72 B

    prep_all<<<2313, 256, 0, stream>>>(wconv, wclf, bclf, wmf, wdiff, bdiff);
    conv3x3_mfma_f64<<<1024, 256, 0, stream>>>(xin, wmf, bconv, y);
    head_clf2w<<<8192, 256, 0, stream>>>(y, wdiff, bdiff, dlog);
    topk1000<<<8, 1024, 0, stream>>>(dlog, selidx);
    decode_boxes2<<<2000, 256, 0, stream>>>(y, selidx, wregp, bregp, anchors, boxes);
    nms_fused_k<<<8, 1024, 0, stream>>>(boxes, out);
}

// Round 15
// 934.515 us; speedup vs baseline: 1.3928x; 1.3928x over previous
//
#include <hip/hip_runtime.h>

typedef unsigned long long ULL;
typedef double v4d __attribute__((ext_vector_type(4)));

// B=8, Cin=Cout=256, H=W=64, A=9, N=36864/batch, PRE=1000, POST=300

__device__ __forceinline__ ULL fkey64(double f) {
    ULL u = (ULL)__double_as_longlong(f);
    return (u & 0x8000000000000000ull) ? ~u : (u | 0x8000000000000000ull);
}

// ---------------- kernel 1: prep (merged): MFMA weight layout + clf diff weights ------------
// wmf layout: [cc 0..63][cg 0..3][tap 0..8][cil 0..3][co 0..63] fp64 (4.72 MB). Each (cc,cg)
// slab is 2304 doubles = 18432 B contiguous -> conv stages it linearly (9 doubles/thread).
__global__ void prep_all(const float* __restrict__ wconv,
                         const float* __restrict__ wclf, const float* __restrict__ bclf,
                         double* __restrict__ wmf,
                         double* __restrict__ wdiff, double* __restrict__ bdiff) {
    int blk = blockIdx.x;
    if (blk < 2304) {
        int e = blk * 256 + threadIdx.x;   // 589824 total
        int co = e & 63;
        int r = e >> 6;                    // 0..9215 = ((cc*4+cg)*9+tap)*4+cil
        int cil = r & 3;
        int r2 = r >> 2;                   // (cc*4+cg)*9+tap
        int tap = r2 % 9;
        int r3 = r2 / 9;                   // cc*4+cg
        int cg = r3 & 3;
        int cc = r3 >> 2;
        int ci = cc * 4 + cil;
        int gco = cg * 64 + co;
        wmf[e] = (double)wconv[(gco * 256 + ci) * 9 + tap];
    } else {
        int a = blk - 2304;                // 0..8
        int c = threadIdx.x;
        wdiff[a * 256 + c] = (double)wclf[(9 + a) * 256 + c] - (double)wclf[a * 256 + c];
        if (c == 0) bdiff[a] = (double)bclf[9 + a] - (double)bclf[a];
    }
}

// ---------------- kernel 2: 3x3 conv + bias + relu via v_mfma_f64_16x16x4, M=128 ------------
// EXACT r12 kernel (619-630 us, MfmaUtil 84-85%). Ladder settled: 857(VALU)->682->650->
// 629/619(M=128); streaming=708 refuted (r13); dbuf=707 refuted (r7); 6blk=667 refuted (r10).
// Implicit GEMM: M=128 (two rows/block), N=64 (cg quarter), K=2304 (64 chunks x 9 taps x 4ci).
// Per chunk the SAME 18KB w slab feeds 72 MFMAs/wave; each B-frag ds_read feeds 2 MFMAs.
// Wave w owns cols [w*16,w*16+16) of BOTH rows x all 4 N-tiles (acc 2x4 v4d = 64 VGPR).
// A/B layouts cardinality-forced: A[m=lane&15][k=lane>>4], B[k=lane>>4][n=lane&15];
// D layout via runtime probe (2 throwaway MFMAs) -- correct for ANY f64 D lane-mapping.
__global__ __launch_bounds__(256)
__attribute__((amdgpu_waves_per_eu(4, 4)))
void conv3x3_mfma_f64(
    const float* __restrict__ xin, const double* __restrict__ wmf,
    const float* __restrict__ bias, double* __restrict__ y)
{
    __shared__ double wlds[2304];   // [tap][cil][co64]  18432 B
    __shared__ float  xs[1152];     // [cil 0..3][row 0..3 = h0-1..h0+2][72]; col c = input col c-1

    const int t = threadIdx.x;
    const int blk = blockIdx.x;
    const int b = blk >> 7;            // 8 batches x 128 blocks
    const int rp = (blk >> 2) & 31;    // row pair
    const int cg = blk & 3;
    const int h0 = rp * 2;
    const int lane = t & 63;
    const int wid = t >> 6;            // wave id = column tile
    const int arow = lane & 15;        // A-row (pixel in tile) == B-col (co in tile)
    const int kq = lane >> 4;          // k index (cil) for A and B frags

    // x staging decomposition: 4 cil * 4 rows (h0-1..h0+2) * 66 cols = 1056 elems
    int x_ld[5], x_go[5];
#pragma unroll
    for (int i = 0; i < 5; i++) {
        int e = t + i * 256;
        x_ld[i] = -1; x_go[i] = -1;
        if (e < 1056) {
            int cil = e / 264; int rem = e - cil * 264;
            int row = rem / 66; int c = rem - row * 66;
            int hh = h0 - 1 + row; int col = c - 1;
            x_ld[i] = cil * 288 + row * 72 + c;
            if (hh >= 0 && hh < 64 && col >= 0 && col < 64)
                x_go[i] = cil * 4096 + hh * 64 + col;
        }
    }

    const float* xb = xin + (size_t)b * 1048576;
    const double* wsrc = wmf + (size_t)cg * 2304;   // + cc*9216 per chunk

    // ---- D-layout probe: exact (row,col) of acc element g for this lane ----
    v4d pz = {0.0, 0.0, 0.0, 0.0};
    v4d prow = __builtin_amdgcn_mfma_f64_16x16x4f64((double)arow, 1.0, pz, 0, 0, 0);
    v4d pcol = __builtin_amdgcn_mfma_f64_16x16x4f64(1.0, (double)arow, pz, 0, 0, 0);
    int rmap[4], cmap[4];
#pragma unroll
    for (int g = 0; g < 4; g++) {
        rmap[g] = (int)(prow[g] * 0.25 + 0.5);
        cmap[g] = (int)(pcol[g] * 0.25 + 0.5);
    }

    // preload chunk 0 into regs
    float xreg[5];
    double wreg[9];
#pragma unroll
    for (int i = 0; i < 5; i++)
        xreg[i] = (x_ld[i] >= 0 && x_go[i] >= 0) ? xb[x_go[i]] : 0.f;
#pragma unroll
    for (int i = 0; i < 9; i++) wreg[i] = wsrc[t + i * 256];

    v4d acc0[4], acc1[4];              // row h0 / row h0+1
#pragma unroll
    for (int nt = 0; nt < 4; nt++) {
        acc0[nt] = (v4d){0.0, 0.0, 0.0, 0.0};
        acc1[nt] = (v4d){0.0, 0.0, 0.0, 0.0};
    }

    for (int cc = 0; cc < 64; ++cc) {
        __syncthreads();   // previous compute done before LDS overwrite
#pragma unroll
        for (int i = 0; i < 5; i++) if (x_ld[i] >= 0) xs[x_ld[i]] = xreg[i];
#pragma unroll
        for (int i = 0; i < 9; i++) wlds[t + i * 256] = wreg[i];
        __syncthreads();

        // prefetch next chunk into regs (overlaps with compute below)
        if (cc < 63) {
#pragma unroll
            for (int i = 0; i < 5; i++)
                xreg[i] = (x_ld[i] >= 0 && x_go[i] >= 0) ? xb[(cc + 1) * 16384 + x_go[i]] : 0.f;
#pragma unroll
            for (int i = 0; i < 9; i++) wreg[i] = wsrc[(size_t)(cc + 1) * 9216 + t + i * 256];
        }

        // compute chunk cc: 9 taps x (2 A scalars, 4 shared B frags, 8 MFMA)
        const float* xsp = xs + kq * 288 + wid * 16 + arow;
        const double* wsp = wlds + kq * 64 + arow;
#pragma unroll
        for (int kh = 0; kh < 3; kh++) {
#pragma unroll
            for (int kw = 0; kw < 3; kw++) {
                const int tap = kh * 3 + kw;
                double a0 = (double)xsp[kh * 72 + kw];
                double a1 = (double)xsp[(kh + 1) * 72 + kw];
#pragma unroll
                for (int nt = 0; nt < 4; nt++) {
                    double bf = wsp[tap * 256 + nt * 16];
                    acc0[nt] = __builtin_amdgcn_mfma_f64_16x16x4f64(a0, bf, acc0[nt], 0, 0, 0);
                    acc1[nt] = __builtin_amdgcn_mfma_f64_16x16x4f64(a1, bf, acc1[nt], 0, 0, 0);
                }
            }
        }
    }

    // epilogue: bias + relu (fp64), store NHWC fp64 via probed D maps (layout-agnostic)
    const size_t pix0 = (size_t)(b * 4096 + h0 * 64 + wid * 16);
#pragma unroll
    for (int nt = 0; nt < 4; nt++) {
#pragma unroll
        for (int g = 0; g < 4; g++) {
            int co = cg * 64 + nt * 16 + cmap[g];
            double bv = (double)bias[co];
            y[(pix0 + rmap[g]) * 256 + co]      = fmax(acc0[nt][g] + bv, 0.0);
            y[(pix0 + 64 + rmap[g]) * 256 + co] = fmax(acc1[nt][g] + bv, 0.0);
        }
    }
}

// ---------------- kernel 3: clf head, wave-per-pixel (coalesced y + butterfly reduce) -------
__global__ __launch_bounds__(256) void head_clf2w(
    const double* __restrict__ y, const double* __restrict__ wdiff,
    const double* __restrict__ bdiff, double* __restrict__ dlog)
{
    const int px = blockIdx.x * 4 + (threadIdx.x >> 6);   // 0..32767 (= b*4096 + pix)
    const int lane = threadIdx.x & 63;

    const double* yr = y + (size_t)px * 256;
    double yv[4];
#pragma unroll
    for (int k = 0; k < 4; k++) yv[k] = yr[lane + k * 64];

    double s[9];
#pragma unroll
    for (int a = 0; a < 9; a++) {
        const double* wr = wdiff + a * 256;
        double v = 0.0;
#pragma unroll
        for (int k = 0; k < 4; k++) v = fma(wr[lane + k * 64], yv[k], v);
        s[a] = v;
    }
#pragma unroll
    for (int off = 32; off > 0; off >>= 1) {
#pragma unroll
        for (int a = 0; a < 9; a++) s[a] += __shfl_xor(s[a], off);
    }
    if (lane < 9) dlog[(size_t)px * 9 + lane] = s[lane] + bdiff[lane];
}

// ---------------- kernel 4: exact top-1000, radix-select with PARALLEL bucket-find ----------
// r9-verified (-40 us vs serial scan). Wave 0: lane l folds 8 replicas for buckets 4l..4l+3,
// 6-step __shfl_down inclusive suffix sum, __ballot boundary find, 4-way bucket resolve.
// Selection semantics bit-identical to the original serial loop.
__global__ __launch_bounds__(1024, 1) void topk1000(
    const double* __restrict__ dlog, int* __restrict__ selidx)
{
    const int b = blockIdx.x;
    const int t = threadIdx.x;
    const double* d = dlog + (size_t)b * 36864;

    ULL key[36];                      // 36864 = 36 * 1024, coalesced; 72 VGPRs
#pragma unroll
    for (int j = 0; j < 36; j++) key[j] = fkey64(d[t + j * 1024]);

    __shared__ unsigned int hist[2048];   // 8 replicas x 256 buckets
    __shared__ ULL sh_prefix;
    __shared__ unsigned int sh_need;
    const int rep = (t >> 6) & 7;         // wave id mod 8 -> replica

    ULL prefix = 0ull;
    int need = 1000;
    for (int rs = 56; rs >= 0; rs -= 8) {
        hist[t] = 0u; hist[t + 1024] = 0u;
        __syncthreads();
        ULL mhi = (rs == 56) ? 0ull : (~0ull << (rs + 8));
#pragma unroll
        for (int j = 0; j < 36; j++) {
            ULL u = key[j];
            if ((u & mhi) == prefix)
                atomicAdd(&hist[rep * 256 + ((unsigned int)(u >> rs) & 255u)], 1u);
        }
        __syncthreads();
        if (t < 64) {                     // wave 0: fold + parallel bucket-find
            unsigned int c[4];
#pragma unroll
            for (int j = 0; j < 4; j++) {
                unsigned int s = 0u;
#pragma unroll
                for (int rr = 0; rr < 8; rr++) s += hist[rr * 256 + 4 * t + j];
                c[j] = s;
            }
            const unsigned int s4 = c[0] + c[1] + c[2] + c[3];
            unsigned int S = s4;          // inclusive suffix sum across lanes
#pragma unroll
            for (int off = 1; off < 64; off <<= 1) {
                unsigned int o = __shfl_down(S, off);
                if (t + off < 64) S += o;
            }
            ULL m = __ballot(S >= (unsigned int)need);   // bit l set iff S_l >= need
            int lstar = 63 - __builtin_clzll(m);         // m != 0: S_0 = total >= need
            if (t == lstar) {
                const unsigned int T = S - s4;           // suffix of lanes > lstar
                const unsigned int nd = (unsigned int)need;
                int vs; unsigned int ca;                 // bucket, count strictly above it
                if (T + c[3] >= nd)                    { vs = 4 * t + 3; ca = T; }
                else if (T + c[3] + c[2] >= nd)        { vs = 4 * t + 2; ca = T + c[3]; }
                else if (T + c[3] + c[2] + c[1] >= nd) { vs = 4 * t + 1; ca = T + c[3] + c[2]; }
                else                    { vs = 4 * t;     ca = T + c[3] + c[2] + c[1]; }
                sh_prefix = prefix | ((ULL)vs << rs);
                sh_need = nd - ca;
            }
        }
        __syncthreads();
        prefix = sh_prefix;
        need = (int)sh_need;
    }

    const ULL K = prefix;                    // exact fp64 key of the 1000th largest
    const int count_above = 1000 - need;     // strictly greater than K
    __shared__ ULL skey[1024];
    __shared__ int sidx[1024];
    __shared__ unsigned int cgt, ceq;
    if (t == 0) { cgt = 0u; ceq = 0u; }
    skey[t] = ~0ull;
    sidx[t] = 0x7FFFFFFF;
    __syncthreads();
#pragma unroll
    for (int j = 0; j < 36; j++) {
        ULL u = key[j];
        int i = t + j * 1024;
        if (u > K) {
            unsigned int s = atomicAdd(&cgt, 1u);
            skey[s] = ~u; sidx[s] = i;
        } else if (u == K) {
            unsigned int s = atomicAdd(&ceq, 1u) + (unsigned int)count_above;
            if (s < 1024u) { skey[s] = ~u; sidx[s] = i; }
        }
    }
    __syncthreads();
    // bitonic sort ascending on (key, idx): == score desc, index asc on ties
    for (int k = 2; k <= 1024; k <<= 1) {
        for (int j = k >> 1; j > 0; j >>= 1) {
            int ixj = t ^ j;
            if (ixj > t) {
                ULL ka = skey[t], kb = skey[ixj];
                int ia = sidx[t], ib = sidx[ixj];
                bool up = ((t & k) == 0);
                bool gt = (ka > kb) || (ka == kb && ia > ib);
                bool lt = (ka < kb) || (ka == kb && ia < ib);
                if (up ? gt : lt) {
                    skey[t] = kb; skey[ixj] = ka;
                    sidx[t] = ib; sidx[ixj] = ia;
                }
            }
            __syncthreads();
        }
    }
    if (t < 1000) selidx[b * 1000 + t] = sidx[t];
}

// ---------------- kernel 5: reg head, wave-per-roi, direct-L2 weights -----------------------
// r10-verified: no LDS staging (anchor is wave-uniform -> 97% of the old 36KB stage was
// waste); wregp read directly through L2, more resident blocks hide scattered y reads.
__global__ __launch_bounds__(256) void decode_boxes2(
    const double* __restrict__ y, const int* __restrict__ selidx,
    const float* __restrict__ wregp, const float* __restrict__ bregp,
    const float* __restrict__ anchors, double4* __restrict__ boxes)
{
    const int roi  = (blockIdx.x * 256 + threadIdx.x) >> 6;   // 0..7999
    const int lane = threadIdx.x & 63;
    const int b = roi / 1000;
    const int n = selidx[roi];                  // wave-uniform
    const int a = n % 9;
    const int pix = n / 9;

    const double2* yrow = (const double2*)(y + ((size_t)(b * 4096 + pix)) * 256);
    double2 ya = yrow[lane];
    double2 yc = yrow[lane + 64];

    double s[4];
#pragma unroll
    for (int c = 0; c < 4; c++) {
        const float* wp = wregp + (4 * a + c) * 256;
        float2 wa = *(const float2*)(wp + 2 * lane);
        float2 wc = *(const float2*)(wp + 128 + 2 * lane);
        double v = 0.0;
        v = fma((double)wa.x, ya.x, v);
        v = fma((double)wa.y, ya.y, v);
        v = fma((double)wc.x, yc.x, v);
        v = fma((double)wc.y, yc.y, v);
        s[c] = v;
    }
#pragma unroll
    for (int off = 32; off > 0; off >>= 1) {
#pragma unroll
        for (int c = 0; c < 4; c++) s[c] += __shfl_xor(s[c], off);
    }

    if (lane == 0) {
        double a0 = s[0] + (double)bregp[4 * a + 0];
        double a1 = s[1] + (double)bregp[4 * a + 1];
        double a2 = s[2] + (double)bregp[4 * a + 2];
        double a3 = s[3] + (double)bregp[4 * a + 3];
        float4 an = ((const float4*)anchors)[n];
        double ax1 = an.x, ay1 = an.y, ax2 = an.z, ay2 = an.w;
        double aw = ax2 - ax1, ah = ay2 - ay1;
        double cx = 0.5 * (ax1 + ax2), cy = 0.5 * (ay1 + ay2);
        double pcx = a0 * aw + cx, pcy = a1 * ah + cy;
        double pw = exp(a2) * aw, ph = exp(a3) * ah;
        double x1b = pcx - 0.5 * pw, y1b = pcy - 0.5 * ph;
        double x2b = pcx + 0.5 * pw, y2b = pcy + 0.5 * ph;
        x1b = fmin(fmax(x1b, 0.0), 1023.0);
        y1b = fmin(fmax(y1b, 0.0), 1023.0);
        x2b = fmin(fmax(x2b, 0.0), 1023.0);
        y2b = fmin(fmax(y2b, 0.0), 1023.0);
        double4 o; o.x = x1b; o.y = y1b; o.z = x2b; o.w = y2b;
        boxes[roi] = o;
    }
}

// ---------------- kernel 6: NMS suppression bitmask matrix (fp64 IoU) -----------------------
// r15: fusion reverted -- r14's 8-block fused NMS lost 8x mask-build parallelism (64->8 CUs,
// ~+25us) for ~15us of launch savings. Split pair restored (r10-verified).
__global__ __launch_bounds__(1024) void nms_mask_k(
    const double4* __restrict__ boxes, ULL* __restrict__ mask)
{
    int b = blockIdx.x >> 3;
    int sub = blockIdx.x & 7;
    __shared__ double4 bx[1000];
    for (int i = threadIdx.x; i < 1000; i += 1024) bx[i] = boxes[b * 1000 + i];
    __syncthreads();
    for (int ml = threadIdx.x; ml < 2000; ml += 1024) {
        int m = sub * 2000 + ml;
        int i = m >> 4;
        int wc = m & 15;
        ULL bits = 0ull;
        int j0 = wc << 6;
        if (j0 + 63 > i) {
            double4 bi = bx[i];
            double ai = (bi.z - bi.x) * (bi.w - bi.y);
            int js = max(j0, i + 1);
            int je = min(j0 + 64, 1000);
            for (int j = js; j < je; j++) {
                double4 bj = bx[j];
                double lx = fmax(bi.x, bj.x), ly = fmax(bi.y, bj.y);
                double ux = fmin(bi.z, bj.z), uy = fmin(bi.w, bj.w);
                double iw = fmax(ux - lx, 0.0), ih = fmax(uy - ly, 0.0);
                double inter = iw * ih;
                double aj = (bj.z - bj.x) * (bj.w - bj.y);
                double iou = inter / (ai + aj - inter);
                if (iou > 0.7) bits |= (1ull << (j - j0));
            }
        }
        mask[(size_t)b * 16000 + m] = bits;
    }
}

// ---------------- kernel 7: greedy scan from LDS-staged mask + compaction -------------------
// r10-verified: stage the 125KB mask into LDS with all 1024 threads (fits < 160KB), scan
// from LDS so the 16-deep prefetch fully covers latency (cross-XCD global was exposed).
// pf[] indexed ONLY by compile-time constants (r5 bug: dynamic pf[i&15] -> scratch).
__global__ __launch_bounds__(1024) void nms_scan_k(
    const ULL* __restrict__ mask, const double4* __restrict__ boxes,
    float* __restrict__ out)
{
    int b = blockIdx.x;
    int t = threadIdx.x;
    __shared__ ULL smask[16000];   // 128000 B
    __shared__ ULL keepw[16];
    {
        const ULL* mrow = mask + (size_t)b * 16000;
        for (int i = t; i < 16000; i += 1024) smask[i] = mrow[i];
    }
    __syncthreads();
    if (t < 64) {           // wave 0 only
        int lane = t;
        ULL remv = 0ull, cur = 0ull;
        ULL pf[16];
#pragma unroll
        for (int q = 0; q < 16; q++) pf[q] = (lane < 16) ? smask[q * 16 + lane] : 0ull;
        for (int base = 0; base < 1000; base += 16) {
#pragma unroll
            for (int q = 0; q < 16; q++) {
                int i = base + q;
                if (i < 1000) {
                    ULL m = pf[q];
                    int c = i >> 6;
                    ULL mc = __shfl(m, c);
                    bool rem = ((cur >> (i & 63)) & 1ull) != 0ull;
                    if (!rem) { remv |= m; cur |= mc; }
                    if (((i + 1) & 63) == 0) cur = __shfl(remv, (i + 1) >> 6);
                    int nx = i + 16;
                    pf[q] = (lane < 16 && nx < 1000) ? smask[nx * 16 + lane] : 0ull;
                }
            }
        }
        if (lane < 16) keepw[lane] = ~remv;
    }
    __syncthreads();
    if (t < 300) {
        float* row = out + (size_t)(b * 300 + t) * 5;
        row[0] = (float)b; row[1] = 0.f; row[2] = 0.f; row[3] = 0.f; row[4] = 0.f;
    }
    __syncthreads();
    if (t < 1000) {
        ULL kw = keepw[t >> 6];
        if ((kw >> (t & 63)) & 1ull) {
            int pos = (int)__popcll(kw & ((1ull << (t & 63)) - 1ull));
            for (int w = 0; w < (t >> 6); w++) pos += (int)__popcll(keepw[w]);
            if (pos < 300) {
                double4 bv = boxes[b * 1000 + t];
                float* row = out + (size_t)(b * 300 + pos) * 5;
                row[1] = (float)bv.x; row[2] = (float)bv.y;
                row[3] = (float)bv.z; row[4] = (float)bv.w;
            }
        }
    }
}

// ---------------- launcher ----------------
extern "C" void kernel_launch(void* const* d_in, const int* in_sizes, int n_in,
                              void* d_out, int out_size, void* d_ws, size_t ws_size,
                              hipStream_t stream)
{
    const float* xin     = (const float*)d_in[0];
    const float* anchors = (const float*)d_in[2];
    const float* wconv   = (const float*)d_in[3];
    const float* bconv   = (const float*)d_in[4];
    const float* wclf    = (const float*)d_in[5];
    const float* bclf    = (const float*)d_in[6];
    const float* wregp   = (const float*)d_in[7];
    const float* bregp   = (const float*)d_in[8];
    float* out = (float*)d_out;

    // ws layout (~74.2 MB; wmf's region is reused by boxes/mask/selidx after conv):
    char* base = (char*)d_ws;
    double*  y      = (double*)(base);              // 67,108,864 B  [conv out, fp64 NHWC]
    double*  wmf    = (double*)(base + 67108864);   //  4,718,592 B  [live: prep -> conv]
    double4* boxes  = (double4*)(base + 67108864);  //    256,000 B  [live: decode -> end]
    ULL*     mask   = (ULL*)(base + 67364864);      //  1,024,000 B
    int*     selidx = (int*)(base + 68388864);      //     32,000 B
    double*  dlog   = (double*)(base + 71827456);   //  2,359,296 B
    double*  wdiff  = (double*)(base + 74186752);   //     18,432 B
    double*  bdiff  = (double*)(base + 74205184);   //         72 B

    prep_all<<<2313, 256, 0, stream>>>(wconv, wclf, bclf, wmf, wdiff, bdiff);
    conv3x3_mfma_f64<<<1024, 256, 0, stream>>>(xin, wmf, bconv, y);
    head_clf2w<<<8192, 256, 0, stream>>>(y, wdiff, bdiff, dlog);
    topk1000<<<8, 1024, 0, stream>>>(dlog, selidx);
    decode_boxes2<<<2000, 256, 0, stream>>>(y, selidx, wregp, bregp, anchors, boxes);
    nms_mask_k<<<64, 1024, 0, stream>>>(boxes, mask);
    nms_scan_k<<<8, 1024, 0, stream>>>(mask, boxes, out);
}